// Round 1
// baseline (28195.041 us; speedup 1.0000x reference)
//
#include <hip/hip_runtime.h>
#include <math.h>

// DCRNN (2-layer DCGRU) classification, MI355X.
// Strategy R1: one workgroup per batch element (B=32 independent recurrences),
// 256 threads, all cross-node coupling via LDS + __syncthreads. fp32 exact.

#define NB 32   // batch
#define NT 128  // timesteps
#define NNODE 64
#define NH 64   // hidden = input dim

__device__ __forceinline__ float4 ld4(const float* p){ return *(const float4*)p; }
__device__ __forceinline__ void st4(float* p, float4 v){ *(float4*)p = v; }

// thread owns rows m0..m0+3 and cols c0..c0+3 of every 64x64 tile
__device__ __forceinline__ void fill_tile(float (*X)[68], const float* src, int m0, int c0){
#pragma unroll
  for (int i=0;i<4;i++) st4(&X[m0+i][c0], ld4(src + (m0+i)*64 + c0));
}

// O[m][d] = (SUB ? 2*(S@X)[m][d] - XS[m][d] : (S@X)[m][d]),  all 64x64 chunks
template<bool SUB>
__device__ __forceinline__ void smul(const float* S, float (*X)[68],
                                     float (*O)[68], float (*XS)[68], int m0, int c0)
{
  float o[4][4];
#pragma unroll
  for (int i=0;i<4;i++){ o[i][0]=0.f;o[i][1]=0.f;o[i][2]=0.f;o[i][3]=0.f; }
#pragma unroll 4
  for (int n4=0;n4<64;n4+=4){
    float s_[4][4];
#pragma unroll
    for (int i=0;i<4;i++){
      float4 t = ld4(S + (m0+i)*64 + n4);
      s_[i][0]=t.x; s_[i][1]=t.y; s_[i][2]=t.z; s_[i][3]=t.w;
    }
    float4 xv[4];
#pragma unroll
    for (int nn=0;nn<4;nn++) xv[nn] = ld4(&X[n4+nn][c0]);
#pragma unroll
    for (int i=0;i<4;i++){
#pragma unroll
      for (int nn=0;nn<4;nn++){
        float sv = s_[i][nn];
        o[i][0] += sv*xv[nn].x; o[i][1] += sv*xv[nn].y;
        o[i][2] += sv*xv[nn].z; o[i][3] += sv*xv[nn].w;
      }
    }
  }
#pragma unroll
  for (int i=0;i<4;i++){
    float4 r;
    if (SUB){
      float4 xo = ld4(&XS[m0+i][c0]);
      r.x = 2.f*o[i][0]-xo.x; r.y = 2.f*o[i][1]-xo.y;
      r.z = 2.f*o[i][2]-xo.z; r.w = 2.f*o[i][3]-xo.w;
    } else {
      r.x = o[i][0]; r.y = o[i][1]; r.z = o[i][2]; r.w = o[i][3];
    }
    st4(&O[m0+i][c0], r);
  }
}

// acc += A(:,0:64) @ W[krow0 + k][cols]; A-reads are float4 along k (row-contig)
template<bool DUAL>
__device__ __forceinline__ void gemm_acc(float (*A)[68], const float* W,
    int wld, int krow0, int m0, int cA, float (*accA)[4], int cB, float (*accB)[4])
{
#pragma unroll 2
  for (int k4=0;k4<64;k4+=4){
    float a_[4][4];
#pragma unroll
    for (int i=0;i<4;i++){
      float4 t = ld4(&A[m0+i][k4]);
      a_[i][0]=t.x; a_[i][1]=t.y; a_[i][2]=t.z; a_[i][3]=t.w;
    }
#pragma unroll
    for (int kk=0;kk<4;kk++){
      const float* wr = W + (size_t)(krow0+k4+kk)*wld;
      float4 wA = ld4(wr + cA);
      float4 wB;
      if (DUAL) wB = ld4(wr + cB);
#pragma unroll
      for (int i=0;i<4;i++){
        float av = a_[i][kk];
        accA[i][0] += av*wA.x; accA[i][1] += av*wA.y;
        accA[i][2] += av*wA.z; accA[i][3] += av*wA.w;
        if (DUAL){
          accB[i][0] += av*wB.x; accB[i][1] += av*wB.y;
          accB[i][2] += av*wB.z; accB[i][3] += av*wB.w;
        }
      }
    }
  }
}

// one 64-col chunk of a gconv: 5 phases (mats: x, S0x, 2S0(S0x)-x, S1x, 2S1(S1x)-x)
// xs must be filled & synced on entry; ends synced.
template<bool DUAL>
__device__ __forceinline__ void gconv_chunk(const float* S0, const float* S1,
    const float* W, int wld, int ko,
    float (*xs)[68], float (*t1s)[68], float (*t2s)[68],
    int m0, int c0, float (*accA)[4], int cB, float (*accB)[4])
{
#pragma unroll 1
  for (int ph=0; ph<5; ph++){
    if (ph < 4){
      const float* S = (ph < 2) ? S0 : S1;
      float (*si)[68] = (ph & 1) ? t1s : xs;
      float (*so)[68] = (ph & 1) ? t2s : t1s;
      if (ph & 1) smul<true >(S, si, so, xs, m0, c0);
      else        smul<false>(S, si, so, xs, m0, c0);
    }
    float (*A)[68] = (ph==0) ? xs : ((ph==1 || ph==3) ? t1s : t2s);
    gemm_acc<DUAL>(A, W, wld, ph*128 + ko, m0, c0, accA, cB, accB);
    __syncthreads();
  }
}

__device__ __forceinline__ float sigmf(float x){ return 1.f/(1.f+expf(-x)); }

__global__ void __launch_bounds__(256)
dcrnn_kernel(const float* __restrict__ input_seq, const int* __restrict__ seq_lengths,
             const float* __restrict__ S0, const float* __restrict__ S1,
             const float* __restrict__ Wg0, const float* __restrict__ bg0,
             const float* __restrict__ Wc0, const float* __restrict__ bc0,
             const float* __restrict__ Wg1, const float* __restrict__ bg1,
             const float* __restrict__ Wc1, const float* __restrict__ bc1,
             const float* __restrict__ Wp, const float* __restrict__ bp,
             float* __restrict__ out, float* __restrict__ ws)
{
  __shared__ float xs[64][68];
  __shared__ float t1s[64][68];
  __shared__ float t2s[64][68];

  const int b   = blockIdx.x;
  const int tid = threadIdx.x;
  const int m0  = (tid >> 4) * 4;
  const int c0  = (tid & 15) * 4;

  float* h1    = ws + (size_t)b * 4096;
  float* h2    = ws + (size_t)(NB + b) * 4096;
  float* lastb = ws + (size_t)(2*NB + b) * 4096;

  // ws is poisoned each launch: zero both hidden states
  for (int i = tid; i < 4096; i += 256){ h1[i] = 0.f; h2[i] = 0.f; }
  __syncthreads();

  int tl = seq_lengths[b] - 1;
  tl = tl < 0 ? 0 : (tl > NT-1 ? NT-1 : tl);

#pragma unroll 1
  for (int t = 0; t < NT; t++){
#pragma unroll 1
    for (int layer = 0; layer < 2; layer++){
      const float* xt = layer ? h1 : (input_seq + (size_t)(b*NT + t) * 4096);
      float* hb       = layer ? h2 : h1;
      const float* Wg = layer ? Wg1 : Wg0;
      const float* bg = layer ? bg1 : bg0;
      const float* Wc = layer ? Wc1 : Wc0;
      const float* bc = layer ? bc1 : bc0;
      const int capture = (layer == 1) && (t == tl);

      // ---- gconv -> [r|u], sigmoid ----
      float aR[4][4], aU[4][4];
      {
        float4 bR = ld4(bg + c0), bU = ld4(bg + 64 + c0);
#pragma unroll
        for (int i=0;i<4;i++){
          aR[i][0]=bR.x; aR[i][1]=bR.y; aR[i][2]=bR.z; aR[i][3]=bR.w;
          aU[i][0]=bU.x; aU[i][1]=bU.y; aU[i][2]=bU.z; aU[i][3]=bU.w;
        }
      }
      fill_tile(xs, xt, m0, c0); __syncthreads();
      gconv_chunk<true>(S0,S1, Wg, 128, 0,  xs,t1s,t2s, m0,c0, aR, 64+c0, aU);
      fill_tile(xs, hb, m0, c0); __syncthreads();
      gconv_chunk<true>(S0,S1, Wg, 128, 64, xs,t1s,t2s, m0,c0, aR, 64+c0, aU);

      float u[4][4];
#pragma unroll
      for (int i=0;i<4;i++){
#pragma unroll
        for (int j=0;j<4;j++){
          float rv = sigmf(aR[i][j]);
          u[i][j]  = sigmf(aU[i][j]);
          aR[i][j] = rv;
        }
      }
      // r*h in place: xs currently holds h (chunk-1 fill), each thread owns its tile
#pragma unroll
      for (int i=0;i<4;i++){
        float4 hv = ld4(&xs[m0+i][c0]);
        hv.x *= aR[i][0]; hv.y *= aR[i][1]; hv.z *= aR[i][2]; hv.w *= aR[i][3];
        st4(&xs[m0+i][c0], hv);
      }
      __syncthreads();

      // ---- gconv -> c, tanh ----
      float aC[4][4];
      {
        float4 bC = ld4(bc + c0);
#pragma unroll
        for (int i=0;i<4;i++){ aC[i][0]=bC.x; aC[i][1]=bC.y; aC[i][2]=bC.z; aC[i][3]=bC.w; }
      }
      // r*h chunk first (concat position 1 -> ko=64), then reload xt (ko=0)
      gconv_chunk<false>(S0,S1, Wc, 64, 64, xs,t1s,t2s, m0,c0, aC, 0, aC);
      fill_tile(xs, xt, m0, c0); __syncthreads();
      gconv_chunk<false>(S0,S1, Wc, 64, 0,  xs,t1s,t2s, m0,c0, aC, 0, aC);

      // ---- h update ----
#pragma unroll
      for (int i=0;i<4;i++){
        float4 hv = ld4(hb + (m0+i)*64 + c0);
        float4 hn;
        hn.x = u[i][0]*hv.x + (1.f-u[i][0])*tanhf(aC[i][0]);
        hn.y = u[i][1]*hv.y + (1.f-u[i][1])*tanhf(aC[i][1]);
        hn.z = u[i][2]*hv.z + (1.f-u[i][2])*tanhf(aC[i][2]);
        hn.w = u[i][3]*hv.w + (1.f-u[i][3])*tanhf(aC[i][3]);
        st4(hb + (m0+i)*64 + c0, hn);
        if (capture) st4(lastb + (m0+i)*64 + c0, hn);
      }
      __syncthreads();
    }
  }

  // ---- epilogue: logits = relu(last) @ Wp + bp ; out[b] = max over nodes ----
  if (tid < 64){
    int n = tid;
    float4 acc = ld4(bp);
#pragma unroll 4
    for (int j=0;j<64;j+=4){
      float4 v = ld4(lastb + n*64 + j);
      v.x = fmaxf(v.x,0.f); v.y = fmaxf(v.y,0.f); v.z = fmaxf(v.z,0.f); v.w = fmaxf(v.w,0.f);
      float4 w0 = ld4(Wp + (j+0)*4);
      float4 w1 = ld4(Wp + (j+1)*4);
      float4 w2 = ld4(Wp + (j+2)*4);
      float4 w3 = ld4(Wp + (j+3)*4);
      acc.x += v.x*w0.x + v.y*w1.x + v.z*w2.x + v.w*w3.x;
      acc.y += v.x*w0.y + v.y*w1.y + v.z*w2.y + v.w*w3.y;
      acc.z += v.x*w0.z + v.y*w1.z + v.z*w2.z + v.w*w3.z;
      acc.w += v.x*w0.w + v.y*w1.w + v.z*w2.w + v.w*w3.w;
    }
    xs[n][0]=acc.x; xs[n][1]=acc.y; xs[n][2]=acc.z; xs[n][3]=acc.w;
  }
  __syncthreads();
  if (tid < 4){
    float m = xs[0][tid];
#pragma unroll 1
    for (int n=1;n<64;n++) m = fmaxf(m, xs[n][tid]);
    out[b*4 + tid] = m;
  }
}

extern "C" void kernel_launch(void* const* d_in, const int* in_sizes, int n_in,
                              void* d_out, int out_size, void* d_ws, size_t ws_size,
                              hipStream_t stream) {
  const float* input_seq   = (const float*)d_in[0];
  const int*   seq_lengths = (const int*)  d_in[1];
  const float* S0  = (const float*)d_in[2];
  const float* S1  = (const float*)d_in[3];
  const float* Wg0 = (const float*)d_in[4];
  const float* bg0 = (const float*)d_in[5];
  const float* Wc0 = (const float*)d_in[6];
  const float* bc0 = (const float*)d_in[7];
  const float* Wg1 = (const float*)d_in[8];
  const float* bg1 = (const float*)d_in[9];
  const float* Wc1 = (const float*)d_in[10];
  const float* bc1 = (const float*)d_in[11];
  const float* Wp  = (const float*)d_in[12];
  const float* bp  = (const float*)d_in[13];

  dcrnn_kernel<<<dim3(NB), dim3(256), 0, stream>>>(
      input_seq, seq_lengths, S0, S1,
      Wg0, bg0, Wc0, bc0, Wg1, bg1, Wc1, bc1,
      Wp, bp, (float*)d_out, (float*)d_ws);
}

// Round 2
// 8167.173 us; speedup vs baseline: 3.4522x; 3.4522x over previous
//
#include <hip/hip_runtime.h>
#include <stdint.h>

// DCRNN 2-layer DCGRU, MI355X. R2: MFMA split-bf16 (hi+lo, 3-term) for all
// matmuls; one workgroup per batch element; dual-layout LDS mats.

typedef short short8 __attribute__((ext_vector_type(8)));      // 8 bf16 frag
typedef float float4v __attribute__((ext_vector_type(4)));
typedef unsigned short ushort4v __attribute__((ext_vector_type(4)));

#define MF(a,b,c) __builtin_amdgcn_mfma_f32_16x16x32_bf16(a,b,c,0,0,0)

__device__ __forceinline__ unsigned short f2bf(float v){
  unsigned int x = __builtin_bit_cast(unsigned int, v);
  x += 0x7FFFu + ((x >> 16) & 1u);
  return (unsigned short)(x >> 16);
}
__device__ __forceinline__ float bf2f(unsigned short h){
  unsigned int x = ((unsigned int)h) << 16;
  return __builtin_bit_cast(float, x);
}

// ---- LDS layout (u16 units). dual buf: NFhi,NFlo,FNhi,FNlo each 64x72 ----
#define B_XT 0
#define B_T  18432
#define B_H1 36864
#define B_H2 55296
#define B_Q  73728   // NFhi(4096), NFlo(4096), stride 64
#define NFH 0
#define NFL 4608
#define FNH 9216
// total = 4*18432 + 8192 = 81920 u16 = 163840 B (exactly 160 KB)

// ws (u16 offsets): S-frags 0..16384, Wg0 16384, Wc0 180224, Wg1 262144,
// Wc1 425984, capture 507904 (+32*4096)
#define WSF_WG0 16384
#define WSF_WC0 180224
#define WSF_WG1 262144
#define WSF_WC1 425984
#define WSF_CAP 507904

// smul: D = S@X (A = S frags in regs, B = X from FN planes of xb).
// SUB: D = 2*D - sub(x0).  Writes NF planes (+ FN planes if WFN).
template<bool SUB, bool WFN>
__device__ __forceinline__ void smul_do(
    unsigned short* lds, const short8* sA /* [kt*2+pl] */,
    int xb, int ob, int sb, int onstr, int onfh, int onfl,
    int w, int fc, int qd)
{
#pragma unroll
  for (int Nt = 0; Nt < 4; ++Nt){
    float4v acc = {0.f,0.f,0.f,0.f};
#pragma unroll
    for (int kt = 0; kt < 2; ++kt){
      const int boff = xb + FNH + (16*Nt + fc)*72 + 32*kt + 8*qd;
      short8 bh = *(const short8*)(lds + boff);
      short8 bl = *(const short8*)(lds + boff + 4608);
      acc = MF(sA[kt*2+0], bh, acc);
      acc = MF(sA[kt*2+0], bl, acc);
      acc = MF(sA[kt*2+1], bh, acc);
    }
    float v[4];
    if (SUB){
      const int soff = sb + FNH + (16*Nt + fc)*72 + 16*w + 4*qd;
      ushort4v sh = *(const ushort4v*)(lds + soff);
      ushort4v sl = *(const ushort4v*)(lds + soff + 4608);
#pragma unroll
      for (int r = 0; r < 4; ++r) v[r] = 2.f*acc[r] - (bf2f(sh[r]) + bf2f(sl[r]));
    } else {
#pragma unroll
      for (int r = 0; r < 4; ++r) v[r] = acc[r];
    }
    ushort4v oh, ol;
#pragma unroll
    for (int r = 0; r < 4; ++r){
      oh[r] = f2bf(v[r]);
      ol[r] = f2bf(v[r] - bf2f(oh[r]));
    }
    if (WFN){
      const int foff = ob + FNH + (16*Nt + fc)*72 + 16*w + 4*qd;
      *(ushort4v*)(lds + foff) = oh;
      *(ushort4v*)(lds + foff + 4608) = ol;
    }
#pragma unroll
    for (int r = 0; r < 4; ++r){
      const int noff = (16*w + 4*qd + r)*onstr + 16*Nt + fc;
      lds[ob + onfh + noff] = oh[r];
      lds[ob + onfl + noff] = ol[r];
    }
  }
}

// GEMM one 64-col mat: acc[Mt] += mat(NF planes) @ Wfrag[nt][ku0..ku0+1]
template<int NSETS>
__device__ __forceinline__ void gemm_mat(
    const unsigned short* lds, int ab, int anfh, int anfl, int astr,
    const unsigned short* __restrict__ wfr, int ku0, int nt0, int nt1,
    float4v* accA, float4v* accB, int ln, int fc, int qd)
{
#pragma unroll
  for (int kt = 0; kt < 2; ++kt){
    const int ku = ku0 + kt;
    short8 ah[4], al[4];
#pragma unroll
    for (int Mt = 0; Mt < 4; ++Mt){
      const int off = ab + (16*Mt + fc)*astr + 32*kt + 8*qd;
      ah[Mt] = *(const short8*)(lds + anfh + off);
      al[Mt] = *(const short8*)(lds + anfl + off);
    }
    const unsigned short* wb0 = wfr + (size_t)((nt0*20 + ku)*2)*512 + ln*8;
    short8 bh0 = *(const short8*)(wb0);
    short8 bl0 = *(const short8*)(wb0 + 512);
#pragma unroll
    for (int Mt = 0; Mt < 4; ++Mt){
      accA[Mt] = MF(ah[Mt], bh0, accA[Mt]);
      accA[Mt] = MF(ah[Mt], bl0, accA[Mt]);
      accA[Mt] = MF(al[Mt], bh0, accA[Mt]);
    }
    if constexpr (NSETS == 2){
      const unsigned short* wb1 = wfr + (size_t)((nt1*20 + ku)*2)*512 + ln*8;
      short8 bh1 = *(const short8*)(wb1);
      short8 bl1 = *(const short8*)(wb1 + 512);
#pragma unroll
      for (int Mt = 0; Mt < 4; ++Mt){
        accB[Mt] = MF(ah[Mt], bh1, accB[Mt]);
        accB[Mt] = MF(ah[Mt], bl1, accB[Mt]);
        accB[Mt] = MF(al[Mt], bh1, accB[Mt]);
      }
    }
  }
}

// one gconv: 2 chunks x 5 phases (mats x, S0x, 2S0S0x-x, S1x, 2S1S1x-x)
template<int NSETS>
__device__ __forceinline__ void gconv(
    unsigned short* lds, const short8* sfr,
    int xb0, int xb1, int kb0, int kb1,
    const unsigned short* wfr, int nt0, int nt1,
    float4v* accA, float4v* accB,
    int w, int ln, int fc, int qd)
{
#pragma unroll 1
  for (int ch = 0; ch < 2; ++ch){
    const int xb = ch ? xb1 : xb0;
    const int kb = ch ? kb1 : kb0;
    // F1: GEMM(x, j=0) + S0@x -> T
    gemm_mat<NSETS>(lds, xb, NFH, NFL, 72, wfr, 0+kb, nt0, nt1, accA, accB, ln, fc, qd);
    smul_do<false,true>(lds, sfr+0, xb, B_T, 0, 72, NFH, NFL, w, fc, qd);
    __syncthreads();
    // F2: GEMM(T, j=1) + S0@T -> Q (SUB x)
    gemm_mat<NSETS>(lds, B_T, NFH, NFL, 72, wfr, 4+kb, nt0, nt1, accA, accB, ln, fc, qd);
    smul_do<true,false>(lds, sfr+0, B_T, B_Q, xb, 64, 0, 4096, w, fc, qd);
    __syncthreads();
    // F3: GEMM(Q, j=2) + S1@x -> T
    gemm_mat<NSETS>(lds, B_Q, 0, 4096, 64, wfr, 8+kb, nt0, nt1, accA, accB, ln, fc, qd);
    smul_do<false,true>(lds, sfr+4, xb, B_T, 0, 72, NFH, NFL, w, fc, qd);
    __syncthreads();
    // F4: GEMM(T, j=3) + S1@T -> Q (SUB x)
    gemm_mat<NSETS>(lds, B_T, NFH, NFL, 72, wfr, 12+kb, nt0, nt1, accA, accB, ln, fc, qd);
    smul_do<true,false>(lds, sfr+4, B_T, B_Q, xb, 64, 0, 4096, w, fc, qd);
    __syncthreads();
    // F5: GEMM(Q, j=4)
    gemm_mat<NSETS>(lds, B_Q, 0, 4096, 64, wfr, 16+kb, nt0, nt1, accA, accB, ln, fc, qd);
    __syncthreads();
  }
}

__device__ __forceinline__ void layer_step(
    unsigned short* lds, const short8* sfr,
    int xb, int hb,
    const unsigned short* wg, const unsigned short* wc,
    float bgr, float bgu, float bcv,
    bool capture, unsigned short* capb,
    int w, int ln, int fc, int qd)
{
  const int chrow = (16*w + fc)*72;
  float4v aR[4], aU[4];
#pragma unroll
  for (int Mt=0;Mt<4;Mt++){
    aR[Mt] = {bgr,bgr,bgr,bgr};
    aU[Mt] = {bgu,bgu,bgu,bgu};
  }
  // ---- ru gconv: chunk0 = x (k-off 0), chunk1 = h (k-off 64) ----
  gconv<2>(lds, sfr, xb, hb, 0, 2, wg, w, w+4, aR, aU, w, ln, fc, qd);

  // ---- gates: r,u = sigmoid; r*h overwrites h (h_old kept in regs) ----
  float4v uu[4], hold[4];
#pragma unroll
  for (int Mt=0;Mt<4;Mt++){
    const int hoff = hb + FNH + chrow + 16*Mt + 4*qd;
    ushort4v hh = *(const ushort4v*)(lds + hoff);
    ushort4v hl = *(const ushort4v*)(lds + hoff + 4608);
    ushort4v oh, ol;
#pragma unroll
    for (int r=0;r<4;r++){
      float rv = 1.f/(1.f + __expf(-aR[Mt][r]));
      uu[Mt][r] = 1.f/(1.f + __expf(-aU[Mt][r]));
      float hv = bf2f(hh[r]) + bf2f(hl[r]);
      hold[Mt][r] = hv;
      float rh = rv * hv;
      oh[r] = f2bf(rh);
      ol[r] = f2bf(rh - bf2f(oh[r]));
    }
    *(ushort4v*)(lds + hoff) = oh;
    *(ushort4v*)(lds + hoff + 4608) = ol;
#pragma unroll
    for (int r=0;r<4;r++){
      const int noff = (16*Mt + 4*qd + r)*72 + 16*w + fc;
      lds[hb + NFH + noff] = oh[r];
      lds[hb + NFL + noff] = ol[r];
    }
  }
  __syncthreads();

  // ---- c gconv: chunk0 = r*h (k-off 64), chunk1 = x (k-off 0) ----
  float4v aC[4];
#pragma unroll
  for (int Mt=0;Mt<4;Mt++) aC[Mt] = {bcv,bcv,bcv,bcv};
  gconv<1>(lds, sfr, hb, xb, 2, 0, wc, w, 0, aC, aC, w, ln, fc, qd);

  // ---- h update: hn = u*h_old + (1-u)*tanh(c) ----
#pragma unroll
  for (int Mt=0;Mt<4;Mt++){
    ushort4v oh, ol;
#pragma unroll
    for (int r=0;r<4;r++){
      float x = fminf(aC[Mt][r], 15.f);
      float e = __expf(2.f*x);
      float cv = (e - 1.f)/(e + 1.f);
      float u1 = uu[Mt][r];
      float hn = u1*hold[Mt][r] + (1.f - u1)*cv;
      oh[r] = f2bf(hn);
      ol[r] = f2bf(hn - bf2f(oh[r]));
    }
    const int hoff = hb + FNH + chrow + 16*Mt + 4*qd;
    *(ushort4v*)(lds + hoff) = oh;
    *(ushort4v*)(lds + hoff + 4608) = ol;
#pragma unroll
    for (int r=0;r<4;r++){
      const int noff = (16*Mt + 4*qd + r)*72 + 16*w + fc;
      lds[hb + NFH + noff] = oh[r];
      lds[hb + NFL + noff] = ol[r];
      if (capture) capb[(16*Mt + 4*qd + r)*64 + 16*w + fc] = oh[r];
    }
  }
  __syncthreads();
}

__global__ void __launch_bounds__(256)
dcrnn_main(const float* __restrict__ input_seq, const int* __restrict__ seq_lengths,
           const float* __restrict__ bg0, const float* __restrict__ bc0,
           const float* __restrict__ bg1, const float* __restrict__ bc1,
           const float* __restrict__ Wp, const float* __restrict__ bp,
           const unsigned short* __restrict__ frags, unsigned short* __restrict__ cap,
           float* __restrict__ out)
{
  extern __shared__ unsigned short lds[];
  const int tid = threadIdx.x;
  const int w = tid >> 6, ln = tid & 63, fc = ln & 15, qd = ln >> 4;
  const int b = blockIdx.x;

  // zero h1,h2 (all 4 planes each)
  unsigned int* l32 = (unsigned int*)lds;
  for (int i = 18432 + tid; i < 36864; i += 256) l32[i] = 0u;

  // S-frags -> regs: sfr[sup*4 + kt*2 + pl], Mt = w
  short8 sfr[8];
#pragma unroll
  for (int sup=0; sup<2; ++sup)
#pragma unroll
    for (int kt=0; kt<2; ++kt)
#pragma unroll
      for (int pl=0; pl<2; ++pl)
        sfr[sup*4+kt*2+pl] =
          *(const short8*)(frags + (size_t)((((sup*2+pl)*4 + w)*2 + kt)*512 + ln*8));

  const unsigned short* WG0 = frags + WSF_WG0;
  const unsigned short* WC0 = frags + WSF_WC0;
  const unsigned short* WG1 = frags + WSF_WG1;
  const unsigned short* WC1 = frags + WSF_WC1;

  const float bg0r = bg0[16*w + fc], bg0u = bg0[64 + 16*w + fc];
  const float bg1r = bg1[16*w + fc], bg1u = bg1[64 + 16*w + fc];
  const float bc0v = bc0[16*w + fc], bc1v = bc1[16*w + fc];

  int tl = seq_lengths[b] - 1; tl = tl < 0 ? 0 : (tl > 127 ? 127 : tl);
  unsigned short* capb = cap + b*4096;
  __syncthreads();

#pragma unroll 1
  for (int ts = 0; ts < 256; ++ts){
    const int t = ts >> 1, layer = ts & 1;
    if (!layer){
      // fill xt NF planes from global (fp32 -> hi/lo)
      {
        const int node = tid >> 2, fg = (tid & 3)*16;
        const float* src = input_seq + ((size_t)b*128 + t)*4096 + node*64 + fg;
        short8 h0v, h1v, l0v, l1v;
#pragma unroll
        for (int i = 0; i < 16; i += 4){
          float4v v = *(const float4v*)(src + i);
#pragma unroll
          for (int j=0;j<4;j++){
            unsigned short hh = f2bf(v[j]);
            unsigned short llv = f2bf(v[j] - bf2f(hh));
            if (i+j < 8){ h0v[i+j] = (short)hh; l0v[i+j] = (short)llv; }
            else        { h1v[i+j-8] = (short)hh; l1v[i+j-8] = (short)llv; }
          }
        }
        short8* d0 = (short8*)(lds + B_XT + NFH + node*72 + fg);
        d0[0] = h0v; d0[1] = h1v;
        short8* d1 = (short8*)(lds + B_XT + NFL + node*72 + fg);
        d1[0] = l0v; d1[1] = l1v;
      }
      __syncthreads();
      // transpose pass -> FN planes
      {
        const int feat = tid >> 2, ng = (tid & 3)*16;
        short8 h0v, h1v, l0v, l1v;
#pragma unroll
        for (int i=0;i<16;i++){
          unsigned short hh = lds[B_XT + NFH + (ng+i)*72 + feat];
          unsigned short llv = lds[B_XT + NFL + (ng+i)*72 + feat];
          if (i < 8){ h0v[i] = (short)hh; l0v[i] = (short)llv; }
          else      { h1v[i-8] = (short)hh; l1v[i-8] = (short)llv; }
        }
        short8* d0 = (short8*)(lds + B_XT + FNH + feat*72 + ng);
        d0[0] = h0v; d0[1] = h1v;
        short8* d1 = (short8*)(lds + B_XT + FNH + 4608 + feat*72 + ng);
        d1[0] = l0v; d1[1] = l1v;
      }
      __syncthreads();
    }
    const int xb = layer ? B_H1 : B_XT;
    const int hb = layer ? B_H2 : B_H1;
    const unsigned short* wg = layer ? WG1 : WG0;
    const unsigned short* wc = layer ? WC1 : WC0;
    const float r0 = layer ? bg1r : bg0r;
    const float u0 = layer ? bg1u : bg0u;
    const float c0 = layer ? bc1v : bc0v;
    const bool cap_now = layer && (t == tl);
    layer_step(lds, sfr, xb, hb, wg, wc, r0, u0, c0, cap_now, capb, w, ln, fc, qd);
  }

  __threadfence();
  __syncthreads();
  // epilogue: logits = relu(last_h) @ Wp + bp; max over nodes
  float* sc = (float*)lds;
  if (tid < 64){
    const unsigned short* hp = cap + b*4096 + tid*64;
    float4v acc = {bp[0], bp[1], bp[2], bp[3]};
#pragma unroll 1
    for (int ch = 0; ch < 64; ++ch){
      float h = fmaxf(bf2f(hp[ch]), 0.f);
      float4v wr = *(const float4v*)(Wp + ch*4);
      acc += h * wr;
    }
    sc[tid*4+0]=acc[0]; sc[tid*4+1]=acc[1]; sc[tid*4+2]=acc[2]; sc[tid*4+3]=acc[3];
  }
  __syncthreads();
  if (tid < 4){
    float m = sc[tid];
#pragma unroll 1
    for (int n=1;n<64;n++) m = fmaxf(m, sc[n*4 + tid]);
    out[b*4 + tid] = m;
  }
}

// ---- prep: frag-pack S (A-layout) and W (B-layout), bf16 hi/lo ----
__global__ void __launch_bounds__(256)
dcrnn_prep(const float* __restrict__ S0, const float* __restrict__ S1,
           const float* __restrict__ Wg0, const float* __restrict__ Wc0,
           const float* __restrict__ Wg1, const float* __restrict__ Wc1,
           unsigned short* __restrict__ frags)
{
  const int uid = blockIdx.x*256 + threadIdx.x;
  if (uid >= 63488) return;
  short8 o;
  unsigned short* dst;
  if (uid < 2048){
    int r = uid;
    const int lane = r & 63; r >>= 6;
    const int kt = r & 1; r >>= 1;
    const int Mt = r & 3; r >>= 2;
    const int pl = r & 1; r >>= 1;
    const float* S = r ? S1 : S0;
    const int m  = 16*Mt + (lane & 15);
    const int k0 = 32*kt + 8*(lane >> 4);
#pragma unroll
    for (int j=0;j<8;j++){
      float v = S[m*64 + k0 + j];
      unsigned short hi = f2bf(v);
      o[j] = (short)(pl ? f2bf(v - bf2f(hi)) : hi);
    }
    dst = frags + (size_t)uid*8;
  } else {
    int u2 = uid - 2048;
    const float* W; int wld; size_t base;
    if      (u2 < 20480){ W = Wg0; wld = 128; base = WSF_WG0; }
    else if (u2 < 30720){ W = Wc0; wld = 64;  base = WSF_WC0; u2 -= 20480; }
    else if (u2 < 51200){ W = Wg1; wld = 128; base = WSF_WG1; u2 -= 30720; }
    else                { W = Wc1; wld = 64;  base = WSF_WC1; u2 -= 51200; }
    const int lane = u2 & 63;
    const int pl   = (u2 >> 6) & 1;
    const int rest = u2 >> 7;          // Nt*20 + ku
    const int ku = rest % 20, Nt = rest / 20;
    const int col   = 16*Nt + (lane & 15);
    const int krow0 = 32*ku + 8*(lane >> 4);
#pragma unroll
    for (int j=0;j<8;j++){
      float v = W[(size_t)(krow0 + j)*wld + col];
      unsigned short hi = f2bf(v);
      o[j] = (short)(pl ? f2bf(v - bf2f(hi)) : hi);
    }
    dst = frags + base + (size_t)u2*8;
  }
  *(short8*)dst = o;
}

extern "C" void kernel_launch(void* const* d_in, const int* in_sizes, int n_in,
                              void* d_out, int out_size, void* d_ws, size_t ws_size,
                              hipStream_t stream) {
  const float* input_seq   = (const float*)d_in[0];
  const int*   seq_lengths = (const int*)  d_in[1];
  const float* S0  = (const float*)d_in[2];
  const float* S1  = (const float*)d_in[3];
  const float* Wg0 = (const float*)d_in[4];
  const float* bg0 = (const float*)d_in[5];
  const float* Wc0 = (const float*)d_in[6];
  const float* bc0 = (const float*)d_in[7];
  const float* Wg1 = (const float*)d_in[8];
  const float* bg1 = (const float*)d_in[9];
  const float* Wc1 = (const float*)d_in[10];
  const float* bc1 = (const float*)d_in[11];
  const float* Wp  = (const float*)d_in[12];
  const float* bp  = (const float*)d_in[13];

  unsigned short* frags = (unsigned short*)d_ws;

  dcrnn_prep<<<dim3(248), dim3(256), 0, stream>>>(S0, S1, Wg0, Wc0, Wg1, Wc1, frags);

  (void)hipFuncSetAttribute((const void*)dcrnn_main,
                            hipFuncAttributeMaxDynamicSharedMemorySize, 163840);
  dcrnn_main<<<dim3(32), dim3(256), 163840, stream>>>(
      input_seq, seq_lengths, bg0, bc0, bg1, bc1, Wp, bp,
      frags, frags + WSF_CAP, (float*)d_out);
}

// Round 3
// 5228.684 us; speedup vs baseline: 5.3924x; 1.5620x over previous
//
#include <hip/hip_runtime.h>
#include <stdint.h>

// DCRNN 2-layer DCGRU, MI355X. R3: project-then-diffuse restructure
// (S commutes with W on feature dim): out = A@W0' + S0(A@W1 + S0(A@2W2))
//                                         + S1(A@W3 + S1(A@2W4)).
// All intermediates flow C-layout -> FN(b64/b128) -> B-operand; no Q plane,
// almost no scalar LDS scatter. 32 blocks x 512 threads (8 waves, 2/SIMD).

typedef short short8 __attribute__((ext_vector_type(8)));
typedef float float4v __attribute__((ext_vector_type(4)));
typedef unsigned short ushort4v __attribute__((ext_vector_type(4)));

#define MF(a,b,c) __builtin_amdgcn_mfma_f32_16x16x32_bf16(a,b,c,0,0,0)

__device__ __forceinline__ unsigned short f2bf(float v){
  unsigned int x = __builtin_bit_cast(unsigned int, v);
  x += 0x7FFFu + ((x >> 16) & 1u);
  return (unsigned short)(x >> 16);
}
__device__ __forceinline__ float bf2f(unsigned short h){
  unsigned int x = ((unsigned int)h) << 16;
  return __builtin_bit_cast(float, x);
}
__device__ __forceinline__ void cvt_hilo(const float4v v, ushort4v& oh, ushort4v& ol){
#pragma unroll
  for (int r=0;r<4;r++){ unsigned short h=f2bf(v[r]); oh[r]=h; ol[r]=f2bf(v[r]-bf2f(h)); }
}

// ---- LDS layout (u16 units). NF planes & Y/I bufs: hi at base, lo at +PLO ----
#define PLO   4608           // 64 rows x 72
#define XNF   0
#define H1NF  9216
#define H2NF  18432
#define RHNF  27648
#define YB1   36864
#define YB2   46080
#define IB0   55296
#define IB1   64512
#define LDS_U16 73728        // 147456 B
#define ZAF   18432          // float index of YB1 (aliased fp32 Z, stride 68)
#define ZBF   23040          // float index of YB2

// ---- ws (u16 offsets) ----
#define WSF_S    0
#define WSF_WG0  16384
#define WSF_WC0  180224
#define WSF_WG1  262144
#define WSF_WC1  425984
#define WSF_CAP  507904

#define TB(grp,j,nt) ((((grp)*5+(j))*4+(nt))*4)

struct AF { short8 h[4]; short8 l[4]; };

__device__ __forceinline__ void load_A(const unsigned short* lds_, int p0, int p1,
                                       int kt, int fc, int qd, AF& a){
  const int pb = (kt<2) ? p0 : p1;
  const int off = 32*(kt&1) + 8*qd;
#pragma unroll
  for (int Mt=0;Mt<4;Mt++){
    const int o = pb + (16*Mt+fc)*72 + off;
    a.h[Mt] = *(const short8*)(lds_+o);
    a.l[Mt] = *(const short8*)(lds_+o+PLO);
  }
}
__device__ __forceinline__ void mm3(const AF& a, short8 bh, short8 bl, float4v* acc){
#pragma unroll
  for (int Mt=0;Mt<4;Mt++){
    acc[Mt]=MF(a.h[Mt],bh,acc[Mt]);
    acc[Mt]=MF(a.h[Mt],bl,acc[Mt]);
    acc[Mt]=MF(a.l[Mt],bh,acc[Mt]);
  }
}
__device__ __forceinline__ void store_Y(unsigned short* lds_, int buf, int nt,
                                        int fc, int qd, const float4v* acc){
#pragma unroll
  for (int Mt=0;Mt<4;Mt++){
    ushort4v oh,ol; cvt_hilo(acc[Mt],oh,ol);
    const int o = buf + (16*nt+fc)*72 + 16*Mt + 4*qd;
    *(ushort4v*)(lds_+o)=oh; *(ushort4v*)(lds_+o+PLO)=ol;
  }
}

// GEMM phase: tile tb0 -> acc0 (kept), optional tile tb1 -> acc1
__device__ __forceinline__ void g_phase(const unsigned short* lds_, int p0,int p1,
    const unsigned short* __restrict__ wfr, int tb0, int tb1,
    float4v* acc0, float4v* acc1, int fc,int qd,int ln)
{
#pragma unroll
  for (int kt=0;kt<4;kt++){
    AF a; load_A(lds_,p0,p1,kt,fc,qd,a);
    {
      const unsigned short* wb = wfr + (size_t)((tb0+kt)*2)*512 + ln*8;
      mm3(a, *(const short8*)wb, *(const short8*)(wb+512), acc0);
    }
    if (tb1 >= 0){
      const unsigned short* wb = wfr + (size_t)((tb1+kt)*2)*512 + ln*8;
      mm3(a, *(const short8*)wb, *(const short8*)(wb+512), acc1);
    }
  }
}

// I_s = Yadd(YB1) + S_s @ Yb(YB2)  -> dst (hi/lo)
__device__ __forceinline__ void inner_smul(unsigned short* lds_, const short8* sf,
  int mt, int np, int fc, int qd, int dst)
{
#pragma unroll
  for (int nn=0;nn<2;nn++){
    const int nt = np+nn;
    float4v acc = {0.f,0.f,0.f,0.f};
#pragma unroll
    for (int kt=0;kt<2;kt++){
      const int bo = YB2 + (16*nt+fc)*72 + 32*kt + 8*qd;
      short8 bh = *(const short8*)(lds_+bo);
      short8 bl = *(const short8*)(lds_+bo+PLO);
      acc = MF(sf[kt*2+0], bh, acc);
      acc = MF(sf[kt*2+0], bl, acc);
      acc = MF(sf[kt*2+1], bh, acc);
    }
    const int yo = YB1 + (16*nt+fc)*72 + 16*mt + 4*qd;
    ushort4v yh = *(const ushort4v*)(lds_+yo);
    ushort4v yl = *(const ushort4v*)(lds_+yo+PLO);
    float4v v;
#pragma unroll
    for (int r=0;r<4;r++) v[r] = acc[r] + bf2f(yh[r]) + bf2f(yl[r]);
    ushort4v oh,ol; cvt_hilo(v,oh,ol);
    const int io = dst + (16*nt+fc)*72 + 16*mt + 4*qd;
    *(ushort4v*)(lds_+io)=oh; *(ushort4v*)(lds_+io+PLO)=ol;
  }
}

// Z_s = S_s @ I_s -> fp32 FN (stride 68 floats)
__device__ __forceinline__ void outer_smul(unsigned short* lds_, const short8* sf,
  int mt, int src, int zf, int fc, int qd)
{
  float* lf = (float*)lds_;
#pragma unroll
  for (int nt=0;nt<4;nt++){
    float4v acc = {0.f,0.f,0.f,0.f};
#pragma unroll
    for (int kt=0;kt<2;kt++){
      const int bo = src + (16*nt+fc)*72 + 32*kt + 8*qd;
      short8 bh=*(const short8*)(lds_+bo), bl=*(const short8*)(lds_+bo+PLO);
      acc=MF(sf[kt*2+0],bh,acc); acc=MF(sf[kt*2+0],bl,acc); acc=MF(sf[kt*2+1],bh,acc);
    }
    *(float4v*)(lf + zf + (16*nt+fc)*68 + 16*mt + 4*qd) = acc;
  }
}

// full group: g1..g5, leaves pre-activation parts: gacc (regs, waves 0-3) + ZA+ZB
__device__ __forceinline__ void group_pre(unsigned short* lds_,
  int p0, int p1, const unsigned short* __restrict__ wfr, int grp, float bias,
  float4v* gacc, const short8* s0f, const short8* s1f,
  int w, int ln, int fc, int qd)
{
  const int mt = w & 3;
  const int np = (w >> 2) * 2;
  {
    float4v a1[4] = {{0.f,0.f,0.f,0.f},{0.f,0.f,0.f,0.f},{0.f,0.f,0.f,0.f},{0.f,0.f,0.f,0.f}};
    if (w < 4){
#pragma unroll
      for (int Mt=0;Mt<4;Mt++) gacc[Mt] = (float4v){bias,bias,bias,bias};
      g_phase(lds_,p0,p1,wfr, TB(grp,0,w), TB(grp,1,w), gacc, a1, fc,qd,ln);
      store_Y(lds_, YB1, w, fc,qd, a1);
    } else {
      g_phase(lds_,p0,p1,wfr, TB(grp,2,w-4), -1, a1, a1, fc,qd,ln);
      store_Y(lds_, YB2, w-4, fc,qd, a1);
    }
  }
  __syncthreads();
  inner_smul(lds_, s0f, mt, np, fc,qd, IB0);
  __syncthreads();
  {
    float4v a1[4] = {{0.f,0.f,0.f,0.f},{0.f,0.f,0.f,0.f},{0.f,0.f,0.f,0.f},{0.f,0.f,0.f,0.f}};
    if (w < 4){
      g_phase(lds_,p0,p1,wfr, TB(grp,3,w), -1, a1, a1, fc,qd,ln);
      store_Y(lds_, YB1, w, fc,qd, a1);
    } else {
      g_phase(lds_,p0,p1,wfr, TB(grp,4,w-4), -1, a1, a1, fc,qd,ln);
      store_Y(lds_, YB2, w-4, fc,qd, a1);
    }
  }
  __syncthreads();
  inner_smul(lds_, s1f, mt, np, fc,qd, IB1);
  __syncthreads();
  if (w < 4) outer_smul(lds_, s0f, mt, IB0, ZAF, fc,qd);
  else       outer_smul(lds_, s1f, mt, IB1, ZBF, fc,qd);
  __syncthreads();
}

__device__ __forceinline__ void read_pre(const unsigned short* lds_,
  const float4v* gacc, float4v* pre, int w, int fc, int qd)
{
  const float* lf = (const float*)lds_;
#pragma unroll
  for (int Mt=0;Mt<4;Mt++){
    float4v za = *(const float4v*)(lf + ZAF + (16*w+fc)*68 + 16*Mt + 4*qd);
    float4v zb = *(const float4v*)(lf + ZBF + (16*w+fc)*68 + 16*Mt + 4*qd);
    pre[Mt] = gacc[Mt] + za + zb;
  }
}

__device__ __forceinline__ void scatter_NF(unsigned short* lds_, int plane,
  int w, int fc, int qd, const ushort4v* oh, const ushort4v* ol)
{
#pragma unroll
  for (int Mt=0;Mt<4;Mt++){
#pragma unroll
    for (int r=0;r<4;r++){
      const int o = plane + (16*Mt+4*qd+r)*72 + 16*w+fc;
      lds_[o] = oh[Mt][r]; lds_[o+PLO] = ol[Mt][r];
    }
  }
}

__global__ void __launch_bounds__(512, 2)
dcrnn_main(const float* __restrict__ input_seq, const int* __restrict__ seq_lengths,
           const float* __restrict__ bg0, const float* __restrict__ bc0,
           const float* __restrict__ bg1, const float* __restrict__ bc1,
           const float* __restrict__ Wp, const float* __restrict__ bp,
           const unsigned short* __restrict__ frags, unsigned short* __restrict__ cap,
           float* __restrict__ out)
{
  extern __shared__ unsigned short lds_[];
  const int tid = threadIdx.x;
  const int w = tid >> 6, ln = tid & 63, fc = ln & 15, qd = ln >> 4;
  const int b = blockIdx.x;

  // zero h1,h2 NF planes (hi+lo): u16 [9216, 27648) -> u32 [4608, 13824)
  {
    unsigned int* l32 = (unsigned int*)lds_;
    for (int i = 4608 + tid; i < 13824; i += 512) l32[i] = 0u;
  }

  // S-frags: both supports for this wave's mt = w&3
  short8 s0f[4], s1f[4];
  {
    const int mt = w & 3;
#pragma unroll
    for (int kt=0;kt<2;kt++)
#pragma unroll
      for (int pl=0;pl<2;pl++){
        s0f[kt*2+pl] = *(const short8*)(frags + (size_t)((((0*2+pl)*4+mt)*2+kt)*512 + ln*8));
        s1f[kt*2+pl] = *(const short8*)(frags + (size_t)((((1*2+pl)*4+mt)*2+kt)*512 + ln*8));
      }
  }
  const unsigned short* WG0f = frags + WSF_WG0;
  const unsigned short* WC0f = frags + WSF_WC0;
  const unsigned short* WG1f = frags + WSF_WG1;
  const unsigned short* WC1f = frags + WSF_WC1;

  const int gcol = 16*w + fc;
  const float br0 = (w<4) ? bg0[gcol]      : 0.f;
  const float bu0 = (w<4) ? bg0[64+gcol]   : 0.f;
  const float bc0v= (w<4) ? bc0[gcol]      : 0.f;
  const float br1 = (w<4) ? bg1[gcol]      : 0.f;
  const float bu1 = (w<4) ? bg1[64+gcol]   : 0.f;
  const float bc1v= (w<4) ? bc1[gcol]      : 0.f;

  int tl = seq_lengths[b] - 1; tl = tl < 0 ? 0 : (tl > 127 ? 127 : tl);
  unsigned short* capb = cap + (size_t)b*4096;

  float4v h1o[4], h2o[4], uv[4], gacc[4];
#pragma unroll
  for (int Mt=0;Mt<4;Mt++){ h1o[Mt]=(float4v){0.f,0.f,0.f,0.f}; h2o[Mt]=(float4v){0.f,0.f,0.f,0.f}; }

#pragma unroll 1
  for (int t = 0; t < 128; ++t){
    // stage xt -> XNF hi/lo (512 threads: node=tid>>3, f0=(tid&7)*8)
    {
      const int node = tid >> 3, f0 = (tid & 7)*8;
      const float* src = input_seq + (((size_t)b*128 + t)*64 + node)*64 + f0;
      float4v v0 = *(const float4v*)(src);
      float4v v1 = *(const float4v*)(src+4);
      short8 hh, ll;
#pragma unroll
      for (int j=0;j<4;j++){
        unsigned short h0=f2bf(v0[j]); hh[j]=(short)h0; ll[j]=(short)f2bf(v0[j]-bf2f(h0));
        unsigned short h1=f2bf(v1[j]); hh[4+j]=(short)h1; ll[4+j]=(short)f2bf(v1[j]-bf2f(h1));
      }
      *(short8*)(lds_ + XNF + node*72 + f0) = hh;
      *(short8*)(lds_ + XNF + PLO + node*72 + f0) = ll;
    }
    __syncthreads();

#pragma unroll 1
    for (int L = 0; L < 2; ++L){
      const int xp = L ? H1NF : XNF;
      const int hp = L ? H2NF : H1NF;
      const unsigned short* wg = L ? WG1f : WG0f;
      const unsigned short* wc = L ? WC1f : WC0f;
      const float brv = L ? br1 : br0;
      const float buv = L ? bu1 : bu0;
      const float bcv = L ? bc1v : bc0v;
      const bool cap_now = (L==1) && (t==tl);

      // ---- group r ----
      group_pre(lds_, xp, hp, wg, 0, brv, gacc, s0f, s1f, w, ln, fc, qd);
      if (w < 4){
        float4v pre[4]; read_pre(lds_, gacc, pre, w, fc, qd);
        ushort4v oh[4], ol[4];
#pragma unroll
        for (int Mt=0;Mt<4;Mt++){
          float4v hv = L ? h2o[Mt] : h1o[Mt];
          float4v rh;
#pragma unroll
          for (int r=0;r<4;r++){
            float rv = 1.f/(1.f+__expf(-pre[Mt][r]));
            rh[r] = rv*hv[r];
          }
          cvt_hilo(rh, oh[Mt], ol[Mt]);
        }
        scatter_NF(lds_, RHNF, w, fc, qd, oh, ol);
      }
      __syncthreads();

      // ---- group u ----
      group_pre(lds_, xp, hp, wg, 1, buv, gacc, s0f, s1f, w, ln, fc, qd);
      if (w < 4){
        float4v pre[4]; read_pre(lds_, gacc, pre, w, fc, qd);
#pragma unroll
        for (int Mt=0;Mt<4;Mt++){
#pragma unroll
          for (int r=0;r<4;r++) uv[Mt][r] = 1.f/(1.f+__expf(-pre[Mt][r]));
        }
      }
      __syncthreads();

      // ---- group c + update ----
      group_pre(lds_, xp, RHNF, wc, 0, bcv, gacc, s0f, s1f, w, ln, fc, qd);
      if (w < 4){
        float4v pre[4]; read_pre(lds_, gacc, pre, w, fc, qd);
        ushort4v oh[4], ol[4];
#pragma unroll
        for (int Mt=0;Mt<4;Mt++){
          float4v hv = L ? h2o[Mt] : h1o[Mt];
          float4v hn;
#pragma unroll
          for (int r=0;r<4;r++){
            float x = fminf(pre[Mt][r], 15.f);
            float e = __expf(2.f*x);
            float cv = (e-1.f)/(e+1.f);
            float u1 = uv[Mt][r];
            hn[r] = u1*hv[r] + (1.f-u1)*cv;
          }
          if (L) h2o[Mt]=hn; else h1o[Mt]=hn;
          cvt_hilo(hn, oh[Mt], ol[Mt]);
        }
        scatter_NF(lds_, hp, w, fc, qd, oh, ol);
        if (cap_now){
#pragma unroll
          for (int Mt=0;Mt<4;Mt++)
#pragma unroll
            for (int r=0;r<4;r++)
              capb[(16*Mt+4*qd+r)*64 + 16*w+fc] = oh[Mt][r];
        }
      }
      __syncthreads();
    }
  }

  __threadfence();
  __syncthreads();
  // epilogue: logits = relu(last_h2) @ Wp + bp; max over nodes
  float* sc = (float*)lds_;
  if (tid < 64){
    const unsigned short* hpx = cap + (size_t)b*4096 + tid*64;
    float4v acc = {bp[0], bp[1], bp[2], bp[3]};
#pragma unroll 1
    for (int ch = 0; ch < 64; ++ch){
      float h = fmaxf(bf2f(hpx[ch]), 0.f);
      float4v wr = *(const float4v*)(Wp + ch*4);
      acc += h * wr;
    }
    sc[tid*4+0]=acc[0]; sc[tid*4+1]=acc[1]; sc[tid*4+2]=acc[2]; sc[tid*4+3]=acc[3];
  }
  __syncthreads();
  if (tid < 4){
    float m = sc[tid];
#pragma unroll 1
    for (int n=1;n<64;n++) m = fmaxf(m, sc[n*4 + tid]);
    out[b*4 + tid] = m;
  }
}

// ---- prep: S-frags (A-layout) + combined/folded W-frags (B-layout), hi/lo ----
__global__ void __launch_bounds__(256)
dcrnn_prep(const float* __restrict__ S0, const float* __restrict__ S1,
           const float* __restrict__ Wg0, const float* __restrict__ Wc0,
           const float* __restrict__ Wg1, const float* __restrict__ Wc1,
           unsigned short* __restrict__ frags)
{
  const int uid = blockIdx.x*256 + threadIdx.x;
  if (uid >= 63488) return;
  short8 o;
  unsigned short* dst;
  if (uid < 2048){
    int r = uid;
    const int lane = r & 63; r >>= 6;
    const int kt = r & 1; r >>= 1;
    const int Mt = r & 3; r >>= 2;
    const int pl = r & 1; r >>= 1;
    const float* S = r ? S1 : S0;
    const int m  = 16*Mt + (lane & 15);
    const int k0 = 32*kt + 8*(lane >> 4);
#pragma unroll
    for (int j=0;j<8;j++){
      float v = S[m*64 + k0 + j];
      unsigned short hi = f2bf(v);
      o[j] = (short)(pl ? f2bf(v - bf2f(hi)) : hi);
    }
    dst = frags + (size_t)uid*8;
  } else {
    int u2 = uid - 2048;
    const float* W; int wld; size_t base;
    if      (u2 < 20480){ W = Wg0; wld = 128; base = WSF_WG0; }
    else if (u2 < 30720){ W = Wc0; wld = 64;  base = WSF_WC0; u2 -= 20480; }
    else if (u2 < 51200){ W = Wg1; wld = 128; base = WSF_WG1; u2 -= 30720; }
    else                { W = Wc1; wld = 64;  base = WSF_WC1; u2 -= 51200; }
    const int lane = u2 & 63;
    const int pl   = (u2 >> 6) & 1;
    const int rest = u2 >> 7;                 // ((grp*5+j)*4+nt)*4+kt
    const int kt = rest & 3;
    const int nt = (rest >> 2) & 3;
    const int j  = (rest >> 4) % 5;
    const int grp= (rest >> 4) / 5;
    const int col = grp*64 + 16*nt + (lane & 15);
    const int k0  = 32*kt + 8*(lane >> 4);
#pragma unroll
    for (int jj=0;jj<8;jj++){
      const int k = k0 + jj;
      float v;
      if (j == 0)
        v = W[(size_t)k*wld + col] - W[(size_t)(256+k)*wld + col] - W[(size_t)(512+k)*wld + col];
      else {
        v = W[(size_t)(j*128 + k)*wld + col];
        if (j == 2 || j == 4) v *= 2.f;
      }
      unsigned short hi = f2bf(v);
      o[jj] = (short)(pl ? f2bf(v - bf2f(hi)) : hi);
    }
    dst = frags + base + (size_t)u2*8;
  }
  *(short8*)dst = o;
}

extern "C" void kernel_launch(void* const* d_in, const int* in_sizes, int n_in,
                              void* d_out, int out_size, void* d_ws, size_t ws_size,
                              hipStream_t stream) {
  const float* input_seq   = (const float*)d_in[0];
  const int*   seq_lengths = (const int*)  d_in[1];
  const float* S0  = (const float*)d_in[2];
  const float* S1  = (const float*)d_in[3];
  const float* Wg0 = (const float*)d_in[4];
  const float* bg0 = (const float*)d_in[5];
  const float* Wc0 = (const float*)d_in[6];
  const float* bc0 = (const float*)d_in[7];
  const float* Wg1 = (const float*)d_in[8];
  const float* bg1 = (const float*)d_in[9];
  const float* Wc1 = (const float*)d_in[10];
  const float* bc1 = (const float*)d_in[11];
  const float* Wp  = (const float*)d_in[12];
  const float* bp  = (const float*)d_in[13];

  unsigned short* frags = (unsigned short*)d_ws;

  dcrnn_prep<<<dim3(248), dim3(256), 0, stream>>>(S0, S1, Wg0, Wc0, Wg1, Wc1, frags);

  (void)hipFuncSetAttribute((const void*)dcrnn_main,
                            hipFuncAttributeMaxDynamicSharedMemorySize, LDS_U16*2);
  dcrnn_main<<<dim3(32), dim3(512), LDS_U16*2, stream>>>(
      input_seq, seq_lengths, bg0, bc0, bg1, bc1, Wp, bp,
      frags, frags + WSF_CAP, (float*)d_out);
}

// Round 4
// 3711.659 us; speedup vs baseline: 7.5963x; 1.4087x over previous
//
#include <hip/hip_runtime.h>
#include <stdint.h>

// DCRNN 2-layer DCGRU, MI355X. R4: (1) single-pass groups (A read once/group,
// 3 syncs/group); (2) layer pipelining: 32 producer blocks (layer0) + 32
// consumer blocks (layer1) linked by per-timestep ring slots + device-scope
// flags in ws. Split-bf16 (hi/lo 3-term) numerics as R2/R3.

typedef short short8 __attribute__((ext_vector_type(8)));
typedef float float4v __attribute__((ext_vector_type(4)));
typedef unsigned short ushort4v __attribute__((ext_vector_type(4)));
typedef unsigned int uint4v __attribute__((ext_vector_type(4)));

#define MF(a,b,c) __builtin_amdgcn_mfma_f32_16x16x32_bf16(a,b,c,0,0,0)

__device__ __forceinline__ unsigned short f2bf(float v){
  unsigned int x = __builtin_bit_cast(unsigned int, v);
  x += 0x7FFFu + ((x >> 16) & 1u);
  return (unsigned short)(x >> 16);
}
__device__ __forceinline__ float bf2f(unsigned short h){
  unsigned int x = ((unsigned int)h) << 16;
  return __builtin_bit_cast(float, x);
}
__device__ __forceinline__ void cvt_hilo(const float4v v, ushort4v& oh, ushort4v& ol){
#pragma unroll
  for (int r=0;r<4;r++){ unsigned short h=f2bf(v[r]); oh[r]=h; ol[r]=f2bf(v[r]-bf2f(h)); }
}

// ---- LDS layout (u16). planes hi at base, lo at +PLO; rows stride 72 ----
#define PLO 4608
#define XP  0        // x (producer) / imported h1 (consumer)
#define HP  9216     // h plane; rh overwrites it (h_old kept in regs)
#define YS0 18432    // Y1 -> I0
#define YS1 27648    // Y2
#define YS2 36864    // Y3 -> I1
#define YS3 46080    // Y4
#define Z0F 27648    // f32 index (u16 55296), stride 68
#define Z1F 32000
#define LDS_BYTES 145408

// ---- ws (u16 offsets) ----
#define WSF_WG0 16384
#define WSF_WC0 180224
#define WSF_WG1 262144
#define WSF_WC1 425984
#define WSF_CAP 507904
#define WSF_FLAG 638976   // int flags[32][128]
#define WSF_DONE 647168   // int done[32]
#define WSF_SLOT 647232   // u16, 32*16 slots * 8192 u16 (4096 u32 packed hi|lo<<16)

#define TB(grp,j,nt) ((((grp)*5+(j))*4+(nt))*4)

__device__ __forceinline__ void store_Y(unsigned short* lds_, int buf, int nt,
                                        int fc, int qd, const float4v* acc){
#pragma unroll
  for (int Mt=0;Mt<4;Mt++){
    ushort4v oh,ol; cvt_hilo(acc[Mt],oh,ol);
    const int o = buf + (16*nt+fc)*72 + 16*Mt + 4*qd;
    *(ushort4v*)(lds_+o)=oh; *(ushort4v*)(lds_+o+PLO)=ol;
  }
}

// P1: Y1..Y4 + gacc(j0,+bias) in one phase. A loaded once per kt.
__device__ __forceinline__ void p1_group(unsigned short* lds_,
    const unsigned short* __restrict__ wfr, int grp, int p0, int p1,
    float bias, float4v* gacc, int w, int ln, int fc, int qd)
{
  const int nt = w & 3;
  const bool lo = (w < 4);
  float4v aY0[4], aY1[4];
#pragma unroll
  for (int Mt=0;Mt<4;Mt++){
    aY0[Mt]=(float4v){0.f,0.f,0.f,0.f};
    aY1[Mt]=(float4v){0.f,0.f,0.f,0.f};
  }
  if (lo){
#pragma unroll
    for (int Mt=0;Mt<4;Mt++) gacc[Mt]=(float4v){bias,bias,bias,bias};
  }
  const int tbG = TB(grp,0,nt);
  const int tbA = lo ? TB(grp,1,nt) : TB(grp,2,nt);
  const int tbB = lo ? TB(grp,3,nt) : TB(grp,4,nt);
#pragma unroll
  for (int kt=0;kt<4;kt++){
    const int pb = (kt<2)? p0 : p1;
    short8 ah[4], al[4];
#pragma unroll
    for (int Mt=0;Mt<4;Mt++){
      const int o = pb + (16*Mt+fc)*72 + 32*(kt&1) + 8*qd;
      ah[Mt]=*(const short8*)(lds_+o);
      al[Mt]=*(const short8*)(lds_+o+PLO);
    }
    if (lo){
      const unsigned short* wb = wfr + (size_t)((tbG+kt)*2)*512 + ln*8;
      short8 bh=*(const short8*)wb, bl=*(const short8*)(wb+512);
#pragma unroll
      for (int Mt=0;Mt<4;Mt++){
        gacc[Mt]=MF(ah[Mt],bh,gacc[Mt]); gacc[Mt]=MF(ah[Mt],bl,gacc[Mt]);
        gacc[Mt]=MF(al[Mt],bh,gacc[Mt]);
      }
    }
    {
      const unsigned short* wb = wfr + (size_t)((tbA+kt)*2)*512 + ln*8;
      short8 bh=*(const short8*)wb, bl=*(const short8*)(wb+512);
#pragma unroll
      for (int Mt=0;Mt<4;Mt++){
        aY0[Mt]=MF(ah[Mt],bh,aY0[Mt]); aY0[Mt]=MF(ah[Mt],bl,aY0[Mt]);
        aY0[Mt]=MF(al[Mt],bh,aY0[Mt]);
      }
    }
    {
      const unsigned short* wb = wfr + (size_t)((tbB+kt)*2)*512 + ln*8;
      short8 bh=*(const short8*)wb, bl=*(const short8*)(wb+512);
#pragma unroll
      for (int Mt=0;Mt<4;Mt++){
        aY1[Mt]=MF(ah[Mt],bh,aY1[Mt]); aY1[Mt]=MF(ah[Mt],bl,aY1[Mt]);
        aY1[Mt]=MF(al[Mt],bh,aY1[Mt]);
      }
    }
  }
  store_Y(lds_, lo? YS0 : YS1, nt, fc, qd, aY0);
  store_Y(lds_, lo? YS2 : YS3, nt, fc, qd, aY1);
}

// P2: I_sup = Yadd + S_sup @ Yb, in place over Yadd slot.
__device__ __forceinline__ void p2_group(unsigned short* lds_,
    const short8* sf, int sup, int mt, int fc, int qd)
{
  const int bS = sup? YS3 : YS1;
  const int aS = sup? YS2 : YS0;
#pragma unroll
  for (int nt=0;nt<4;nt++){
    float4v acc = {0.f,0.f,0.f,0.f};
#pragma unroll
    for (int kt=0;kt<2;kt++){
      const int bo = bS + (16*nt+fc)*72 + 32*kt + 8*qd;
      short8 bh=*(const short8*)(lds_+bo), bl=*(const short8*)(lds_+bo+PLO);
      acc=MF(sf[kt*2+0],bh,acc); acc=MF(sf[kt*2+0],bl,acc); acc=MF(sf[kt*2+1],bh,acc);
    }
    const int ao = aS + (16*nt+fc)*72 + 16*mt + 4*qd;
    ushort4v yh=*(const ushort4v*)(lds_+ao), yl=*(const ushort4v*)(lds_+ao+PLO);
    float4v v;
#pragma unroll
    for (int r=0;r<4;r++) v[r] = acc[r] + bf2f(yh[r]) + bf2f(yl[r]);
    ushort4v oh,ol; cvt_hilo(v,oh,ol);
    *(ushort4v*)(lds_+ao)=oh; *(ushort4v*)(lds_+ao+PLO)=ol;
  }
}

// P3: Z_sup = S_sup @ I_sup -> fp32 [feat][node], stride 68
__device__ __forceinline__ void p3_group(unsigned short* lds_,
    const short8* sf, int sup, int mt, int fc, int qd)
{
  const int iS = sup? YS2 : YS0;
  float* zf = (float*)lds_ + (sup? Z1F : Z0F);
#pragma unroll
  for (int nt=0;nt<4;nt++){
    float4v acc = {0.f,0.f,0.f,0.f};
#pragma unroll
    for (int kt=0;kt<2;kt++){
      const int bo = iS + (16*nt+fc)*72 + 32*kt + 8*qd;
      short8 bh=*(const short8*)(lds_+bo), bl=*(const short8*)(lds_+bo+PLO);
      acc=MF(sf[kt*2+0],bh,acc); acc=MF(sf[kt*2+0],bl,acc); acc=MF(sf[kt*2+1],bh,acc);
    }
    *(float4v*)(zf + (16*nt+fc)*68 + 16*mt + 4*qd) = acc;
  }
}

__device__ __forceinline__ void read_pre(const unsigned short* lds_,
    const float4v* gacc, float4v* pre, int w, int fc, int qd)
{
  const float* lf = (const float*)lds_;
#pragma unroll
  for (int Mt=0;Mt<4;Mt++){
    float4v za = *(const float4v*)(lf + Z0F + (16*w+fc)*68 + 16*Mt + 4*qd);
    float4v zb = *(const float4v*)(lf + Z1F + (16*w+fc)*68 + 16*Mt + 4*qd);
    pre[Mt] = gacc[Mt] + za + zb;
  }
}

__device__ __forceinline__ void scatter_plane(unsigned short* lds_, int plane,
    int w, int fc, int qd, const ushort4v* oh, const ushort4v* ol)
{
#pragma unroll
  for (int Mt=0;Mt<4;Mt++){
#pragma unroll
    for (int r=0;r<4;r++){
      const int o = plane + (16*Mt+4*qd+r)*72 + 16*w+fc;
      lds_[o] = oh[Mt][r]; lds_[o+PLO] = ol[Mt][r];
    }
  }
}

__global__ void __launch_bounds__(512, 2)
dcrnn_main(const float* __restrict__ input_seq, const int* __restrict__ seq_lengths,
           const float* __restrict__ bg0, const float* __restrict__ bc0,
           const float* __restrict__ bg1, const float* __restrict__ bc1,
           const float* __restrict__ Wp, const float* __restrict__ bp,
           unsigned short* __restrict__ ws, float* __restrict__ out)
{
  extern __shared__ unsigned short lds_[];
  const int tid = threadIdx.x;
  const int w = tid>>6, ln = tid&63, fc = ln&15, qd = ln>>4;
  const int role = blockIdx.x >> 5;   // 0 = layer0 producer, 1 = layer1 consumer
  const int b = blockIdx.x & 31;

  const unsigned short* frags = ws;
  int* flags = (int*)(ws + WSF_FLAG) + b*128;
  int* done  = (int*)(ws + WSF_DONE) + b;
  unsigned short* capb = ws + WSF_CAP + (size_t)b*4096;
  unsigned int* slots = (unsigned int*)(ws + WSF_SLOT);

  // zero h plane (hi+lo): u16 [9216,18432) -> u32 [4608,9216)
  { unsigned int* l32 = (unsigned int*)lds_;
    for (int i=4608+tid; i<9216; i+=512) l32[i]=0u; }

  // S-frags for this wave's (sup, mt)
  const int sup = (w>>2)&1, mt = w&3;
  short8 sf[4];
#pragma unroll
  for (int kt=0;kt<2;kt++)
#pragma unroll
    for (int pl=0;pl<2;pl++)
      sf[kt*2+pl] = *(const short8*)(frags + (size_t)((((sup*2+pl)*4+mt)*2+kt)*512 + ln*8));

  const unsigned short* WGf = frags + (role? WSF_WG1 : WSF_WG0);
  const unsigned short* WCf = frags + (role? WSF_WC1 : WSF_WC0);
  const float* bg = role? bg1 : bg0;
  const float* bc = role? bc1 : bc0;
  const int gcol = 16*w+fc;
  const float brv = (w<4)? bg[gcol]    : 0.f;
  const float buv = (w<4)? bg[64+gcol] : 0.f;
  const float bcv = (w<4)? bc[gcol]    : 0.f;

  int tl = 0;
  if (role){ tl = seq_lengths[b]-1; tl = tl<0?0:(tl>127?127:tl); }

  float4v h_old[4], uv[4], gaccR[4], gaccU[4], gaccC[4];
#pragma unroll
  for (int Mt=0;Mt<4;Mt++) h_old[Mt]=(float4v){0.f,0.f,0.f,0.f};
  __syncthreads();

#pragma unroll 1
  for (int t=0; t<128; ++t){
    // ---- phase 0: acquire input into XP ----
    if (role==0){
      if (t>=16 && tid==0){
        while ((int)__hip_atomic_load(done, __ATOMIC_ACQUIRE, __HIP_MEMORY_SCOPE_AGENT) < t-15)
          __builtin_amdgcn_s_sleep(1);
      }
      const int node = tid>>3, f0 = (tid&7)*8;
      const float* src = input_seq + (((size_t)b*128 + t)*64 + node)*64 + f0;
      float4v v0 = *(const float4v*)(src);
      float4v v1 = *(const float4v*)(src+4);
      short8 hh, ll;
#pragma unroll
      for (int j=0;j<4;j++){
        unsigned short h0=f2bf(v0[j]); hh[j]=(short)h0; ll[j]=(short)f2bf(v0[j]-bf2f(h0));
        unsigned short h1=f2bf(v1[j]); hh[4+j]=(short)h1; ll[4+j]=(short)f2bf(v1[j]-bf2f(h1));
      }
      *(short8*)(lds_ + XP + node*72 + f0) = hh;
      *(short8*)(lds_ + XP + PLO + node*72 + f0) = ll;
      __syncthreads();
    } else {
      if (tid==0){
        while (__hip_atomic_load(&flags[t], __ATOMIC_ACQUIRE, __HIP_MEMORY_SCOPE_AGENT) != t+1)
          __builtin_amdgcn_s_sleep(1);
        __threadfence();
      }
      __syncthreads();
      if (w<4){
        const unsigned int* sl = slots + ((size_t)(b*16 + (t&15)))*4096 + (w*64+ln)*16;
#pragma unroll
        for (int Mt=0;Mt<4;Mt++){
          uint4v v = *(const uint4v*)(sl + Mt*4);
#pragma unroll
          for (int r=0;r<4;r++){
            const int o = XP + (16*Mt+4*qd+r)*72 + gcol;
            lds_[o] = (unsigned short)(v[r] & 0xffffu);
            lds_[o+PLO] = (unsigned short)(v[r] >> 16);
          }
        }
      }
      __syncthreads();
      if (tid==0)
        __hip_atomic_store(done, t+1, __ATOMIC_RELEASE, __HIP_MEMORY_SCOPE_AGENT);
    }

    // ---- r group ----
    p1_group(lds_, WGf, 0, XP, HP, brv, gaccR, w, ln, fc, qd);
    __syncthreads();
    p2_group(lds_, sf, sup, mt, fc, qd);
    __syncthreads();
    p3_group(lds_, sf, sup, mt, fc, qd);
    __syncthreads();

    // ---- u group P1 ----
    p1_group(lds_, WGf, 1, XP, HP, buv, gaccU, w, ln, fc, qd);
    __syncthreads();
    // ---- u P2 + gate r (rh -> HP, h_old stays in regs) ----
    p2_group(lds_, sf, sup, mt, fc, qd);
    if (w<4){
      float4v pre[4]; read_pre(lds_, gaccR, pre, w, fc, qd);
      ushort4v oh[4], ol[4];
#pragma unroll
      for (int Mt=0;Mt<4;Mt++){
        float4v rh;
#pragma unroll
        for (int r=0;r<4;r++){
          float rv = 1.f/(1.f+__expf(-pre[Mt][r]));
          rh[r] = rv*h_old[Mt][r];
        }
        cvt_hilo(rh, oh[Mt], ol[Mt]);
      }
      scatter_plane(lds_, HP, w, fc, qd, oh, ol);
    }
    __syncthreads();
    p3_group(lds_, sf, sup, mt, fc, qd);
    __syncthreads();

    // ---- c group P1 + gate u ----
    p1_group(lds_, WCf, 0, XP, HP, bcv, gaccC, w, ln, fc, qd);
    if (w<4){
      float4v pre[4]; read_pre(lds_, gaccU, pre, w, fc, qd);
#pragma unroll
      for (int Mt=0;Mt<4;Mt++)
#pragma unroll
        for (int r=0;r<4;r++) uv[Mt][r] = 1.f/(1.f+__expf(-pre[Mt][r]));
    }
    __syncthreads();
    p2_group(lds_, sf, sup, mt, fc, qd);
    __syncthreads();
    p3_group(lds_, sf, sup, mt, fc, qd);
    __syncthreads();

    // ---- update ----
    if (w<4){
      float4v pre[4]; read_pre(lds_, gaccC, pre, w, fc, qd);
      ushort4v oh[4], ol[4];
#pragma unroll
      for (int Mt=0;Mt<4;Mt++){
        float4v hn;
#pragma unroll
        for (int r=0;r<4;r++){
          float x = fminf(pre[Mt][r], 15.f);
          float e = __expf(2.f*x);
          float cv = (e-1.f)/(e+1.f);
          float u1 = uv[Mt][r];
          hn[r] = u1*h_old[Mt][r] + (1.f-u1)*cv;
        }
        h_old[Mt] = hn;
        cvt_hilo(hn, oh[Mt], ol[Mt]);
      }
      scatter_plane(lds_, HP, w, fc, qd, oh, ol);
      if (role==0){
        unsigned int* sl = slots + ((size_t)(b*16 + (t&15)))*4096 + (w*64+ln)*16;
#pragma unroll
        for (int Mt=0;Mt<4;Mt++){
          uint4v pk;
#pragma unroll
          for (int r=0;r<4;r++)
            pk[r] = (unsigned int)oh[Mt][r] | ((unsigned int)ol[Mt][r] << 16);
          *(uint4v*)(sl + Mt*4) = pk;
        }
      } else if (t==tl){
#pragma unroll
        for (int Mt=0;Mt<4;Mt++)
#pragma unroll
          for (int r=0;r<4;r++)
            capb[(16*Mt+4*qd+r)*64 + gcol] = oh[Mt][r];
      }
    }
    __syncthreads();
    if (role==0 && tid==0){
      __threadfence();
      __hip_atomic_store(&flags[t], t+1, __ATOMIC_RELEASE, __HIP_MEMORY_SCOPE_AGENT);
    }
  }

  if (role==0) return;

  __threadfence();
  __syncthreads();
  // epilogue (consumer): logits = relu(last_h2) @ Wp + bp; max over nodes
  float* sc = (float*)lds_;
  if (tid < 64){
    const unsigned short* hpx = capb + tid*64;
    float4v acc = {bp[0], bp[1], bp[2], bp[3]};
#pragma unroll 1
    for (int ch = 0; ch < 64; ++ch){
      float h = fmaxf(bf2f(hpx[ch]), 0.f);
      const float4v wr = *(const float4v*)(Wp + ch*4);
      acc += h * wr;
    }
    sc[tid*4+0]=acc[0]; sc[tid*4+1]=acc[1]; sc[tid*4+2]=acc[2]; sc[tid*4+3]=acc[3];
  }
  __syncthreads();
  if (tid < 4){
    float m = sc[tid];
#pragma unroll 1
    for (int n=1;n<64;n++) m = fmaxf(m, sc[n*4 + tid]);
    out[b*4 + tid] = m;
  }
}

// ---- prep: S-frags (A-layout) + folded W-frags (B-layout), hi/lo (as R3) ----
__global__ void __launch_bounds__(256)
dcrnn_prep(const float* __restrict__ S0, const float* __restrict__ S1,
           const float* __restrict__ Wg0, const float* __restrict__ Wc0,
           const float* __restrict__ Wg1, const float* __restrict__ Wc1,
           unsigned short* __restrict__ frags)
{
  const int uid = blockIdx.x*256 + threadIdx.x;
  if (uid >= 63488) return;
  short8 o;
  unsigned short* dst;
  if (uid < 2048){
    int r = uid;
    const int lane = r & 63; r >>= 6;
    const int kt = r & 1; r >>= 1;
    const int Mt = r & 3; r >>= 2;
    const int pl = r & 1; r >>= 1;
    const float* S = r ? S1 : S0;
    const int m  = 16*Mt + (lane & 15);
    const int k0 = 32*kt + 8*(lane >> 4);
#pragma unroll
    for (int j=0;j<8;j++){
      float v = S[m*64 + k0 + j];
      unsigned short hi = f2bf(v);
      o[j] = (short)(pl ? f2bf(v - bf2f(hi)) : hi);
    }
    dst = frags + (size_t)uid*8;
  } else {
    int u2 = uid - 2048;
    const float* W; int wld; size_t base;
    if      (u2 < 20480){ W = Wg0; wld = 128; base = WSF_WG0; }
    else if (u2 < 30720){ W = Wc0; wld = 64;  base = WSF_WC0; u2 -= 20480; }
    else if (u2 < 51200){ W = Wg1; wld = 128; base = WSF_WG1; u2 -= 30720; }
    else                { W = Wc1; wld = 64;  base = WSF_WC1; u2 -= 51200; }
    const int lane = u2 & 63;
    const int pl   = (u2 >> 6) & 1;
    const int rest = u2 >> 7;                 // ((grp*5+j)*4+nt)*4+kt
    const int kt = rest & 3;
    const int nt = (rest >> 2) & 3;
    const int j  = (rest >> 4) % 5;
    const int grp= (rest >> 4) / 5;
    const int col = grp*64 + 16*nt + (lane & 15);
    const int k0  = 32*kt + 8*(lane >> 4);
#pragma unroll
    for (int jj=0;jj<8;jj++){
      const int k = k0 + jj;
      float v;
      if (j == 0)
        v = W[(size_t)k*wld + col] - W[(size_t)(256+k)*wld + col] - W[(size_t)(512+k)*wld + col];
      else {
        v = W[(size_t)(j*128 + k)*wld + col];
        if (j == 2 || j == 4) v *= 2.f;
      }
      unsigned short hi = f2bf(v);
      o[jj] = (short)(pl ? f2bf(v - bf2f(hi)) : hi);
    }
    dst = frags + base + (size_t)u2*8;
  }
  *(short8*)dst = o;
}

extern "C" void kernel_launch(void* const* d_in, const int* in_sizes, int n_in,
                              void* d_out, int out_size, void* d_ws, size_t ws_size,
                              hipStream_t stream) {
  const float* input_seq   = (const float*)d_in[0];
  const int*   seq_lengths = (const int*)  d_in[1];
  const float* S0  = (const float*)d_in[2];
  const float* S1  = (const float*)d_in[3];
  const float* Wg0 = (const float*)d_in[4];
  const float* bg0 = (const float*)d_in[5];
  const float* Wc0 = (const float*)d_in[6];
  const float* bc0 = (const float*)d_in[7];
  const float* Wg1 = (const float*)d_in[8];
  const float* bg1 = (const float*)d_in[9];
  const float* Wc1 = (const float*)d_in[10];
  const float* bc1 = (const float*)d_in[11];
  const float* Wp  = (const float*)d_in[12];
  const float* bp  = (const float*)d_in[13];

  unsigned short* ws = (unsigned short*)d_ws;

  dcrnn_prep<<<dim3(248), dim3(256), 0, stream>>>(S0, S1, Wg0, Wc0, Wg1, Wc1, ws);

  (void)hipFuncSetAttribute((const void*)dcrnn_main,
                            hipFuncAttributeMaxDynamicSharedMemorySize, LDS_BYTES);
  dcrnn_main<<<dim3(64), dim3(512), LDS_BYTES, stream>>>(
      input_seq, seq_lengths, bg0, bc0, bg1, bc1, Wp, bp, ws, (float*)d_out);
}